// Round 6
// baseline (516.803 us; speedup 1.0000x reference)
//
#include <hip/hip_runtime.h>
#include <hip/hip_bf16.h>

// Problem constants (B=8192, D=128 from reference setup_inputs)
constexpr int Bh = 8192;
constexpr int Nn = 16384;   // 2*B
constexpr int Dd = 128;
constexpr float EPS = 1e-8f;
constexpr float LN2 = 0.69314718056f;

constexpr int K_TILES = 8;          // tiles per block
constexpr int N_TILES = 8256;       // 128x128 upper-tri tiles (incl diag): 128*129/2
constexpr int N_BLOCKS = N_TILES / K_TILES;   // 1032, exact

typedef short bf16x8 __attribute__((ext_vector_type(8)));
typedef float f32x4 __attribute__((ext_vector_type(4)));

// ---- Kernel 1: fp32 -> bf16, scaled by sqrt(2*log2e) so MFMA dot == sim/tau*log2e ----
__global__ __launch_bounds__(256) void convert_kernel(const float4* __restrict__ za,
                                                      const float4* __restrict__ zb,
                                                      ushort* __restrict__ z,
                                                      float* __restrict__ rowsum,
                                                      float* __restrict__ out) {
    const int t = blockIdx.x * 256 + threadIdx.x;        // 0 .. 524287
    constexpr int Q = (Bh * Dd) / 4;                     // 262144 float4 per input
    const float SCL = 1.69864363f;                       // sqrt(2 * 1.4426950409)
    float4 v = (t < Q) ? za[t] : zb[t - Q];
    union { ushort4 u4; __hip_bfloat16 h[4]; } cv;
    cv.h[0] = __float2bfloat16(v.x * SCL);
    cv.h[1] = __float2bfloat16(v.y * SCL);
    cv.h[2] = __float2bfloat16(v.z * SCL);
    cv.h[3] = __float2bfloat16(v.w * SCL);
    ((ushort4*)z)[t] = cv.u4;
    if (t < Nn) rowsum[t] = 0.f;
    if (t == 0) out[0] = 0.f;          // finalize accumulates via atomics
}

// tile index g -> row tile t (128-row granularity): largest t with cum(t)=t*(257-t)/2 <= g
__device__ __forceinline__ int row_tile_of(int g) {
    int t = (int)((257.0f - sqrtf(66049.0f - 8.0f * (float)g)) * 0.5f);
    t = t < 0 ? 0 : (t > 127 ? 127 : t);
    while (t * (257 - t) / 2 > g) --t;
    while ((t + 1) * (256 - t) / 2 <= g) ++t;
    return t;
}

// row-credit flush: reduce rs over the 16 col-lanes, one atomic per row (log2 domain)
__device__ __forceinline__ void flush_rs(float* __restrict__ rowsum, int rowW,
                                         float (&rs)[2][4], int q, int c) {
#pragma unroll
    for (int s = 0; s < 2; ++s)
#pragma unroll
        for (int r = 0; r < 4; ++r) {
            float v = rs[s][r];
            v += __shfl_xor(v, 1);
            v += __shfl_xor(v, 2);
            v += __shfl_xor(v, 4);
            v += __shfl_xor(v, 8);
            if (c == 0) atomicAdd(&rowsum[rowW + s * 16 + q * 4 + r], v);
            rs[s][r] = 0.f;
        }
}

// col-credit flush (deferred one tile): reduce over q, one atomic per col
__device__ __forceinline__ void colflush(float* __restrict__ rowsum,
                                         float (&csumP)[8], int C0P, int lane, int c) {
#pragma unroll
    for (int st = 0; st < 8; ++st) {
        float v = csumP[st];
        v += __shfl_xor(v, 16);
        v += __shfl_xor(v, 32);
        if (lane < 16) atomicAdd(&rowsum[C0P + st * 16 + c], v);
    }
}

// Stage one 128x128 bf16 B-tile (32 KB) into LDS via global_load_lds width-16.
// LDS layout XOR-swizzled via per-lane permutation of the GLOBAL source (m173);
// ds_read_b128 fragment reads are bank-conflict-free (8 words/bank).
__device__ __forceinline__ void stage_tile(const ushort* __restrict__ z, ushort* lbuf,
                                           int C0, int wave, int lane) {
#pragma unroll
    for (int i = 0; i < 8; ++i) {
        const int chunk = wave * 8 + i;              // 32 chunks of 1 KB
        const int r = (chunk << 2) + (lane >> 4);    // row 0..127 (one col of z)
        const int bl = ((lane & 15) ^ (r & 15)) << 4;  // swizzled byte-in-row
        const char* gp = (const char*)z + (((size_t)(C0 + r)) << 8) + bl;
        ushort* lp = lbuf + (chunk << 9);            // wave-uniform LDS base
        __builtin_amdgcn_global_load_lds((const __attribute__((address_space(1))) void*)gp,
                                         (__attribute__((address_space(3))) void*)lp,
                                         16, 0, 0);
    }
}

// ---- Kernel 2 (templated for ABLATION, R6):
// V=0: the R3 kernel VERBATIM (best measured, 127.5 us) — produces the output.
// V=3: GEMM skeleton only — stage + swizzled ds_read + MFMA + barriers, with
//      softplus/credits/atomics removed (acc kept live via asm, rule #17),
//      repeated 8x inside the kernel so its dispatch is top-5-visible.
//      Reads: skeleton cost = dur(V3)/8. Writes NO memory; launched after
//      finalize so correctness is untouched.
// Diagnosis this feeds: R0-R5 falsified occupancy/atomics/LDS-traffic theories;
// bottom-up pipe model says all pipes sum to ~25 us yet we run at 127 us.
// This splits the 127 into skeleton vs epilogue empirically.
template <int V>
__global__ __launch_bounds__(256) void main_kernel(const ushort* __restrict__ z,
                                                   float* __restrict__ rowsum,
                                                   float* __restrict__ pospair) {
    __shared__ ushort ldsb[2][16384];     // 2 x 32 KB B-tile double buffer

    const int tid = threadIdx.x;
    const int wave = tid >> 6;
    const int lane = tid & 63;
    const int q = lane >> 4;        // quad: 0..3
    const int c = lane & 15;        // 0..15
    const int g0 = blockIdx.x * K_TILES;

    // per-lane swizzled LDS fragment offsets: logical 16B-unit (q+4kt) in row c
    int O[4];
#pragma unroll
    for (int kt = 0; kt < 4; ++kt) O[kt] = (c << 8) + ((((q + 4 * kt) ^ c)) << 4);

    constexpr int REPS = (V == 3) ? 8 : 1;

    for (int rep = 0; rep < REPS; ++rep) {
        int tr = row_tile_of(g0);
        int ct = tr + (g0 - tr * (257 - tr) / 2);

        bf16x8 afrag[2][4];
        float rs[2][4];
#pragma unroll
        for (int s = 0; s < 2; ++s)
#pragma unroll
            for (int r = 0; r < 4; ++r) rs[s][r] = 0.f;

        float csumP[8];
        int C0P = 0;
        bool pendP = false;
        int cur_tr = -1, rowW = 0, cur = 0;

        stage_tile(z, &ldsb[0][0], ct << 7, wave, lane);
        __syncthreads();

        for (int j = 0; j < K_TILES; ++j) {
            const int C0 = ct << 7;
            const bool diag = (ct == tr);

            if (tr != cur_tr) {                 // row-panel change: flush + reload A
                if (V == 0 && cur_tr >= 0) flush_rs(rowsum, rowW, rs, q, c);
                cur_tr = tr;
                rowW = (tr << 7) + wave * 32;   // this wave's 32-row base
#pragma unroll
                for (int s = 0; s < 2; ++s) {
                    const ushort* ap = z + (size_t)(rowW + s * 16 + c) * Dd;
#pragma unroll
                    for (int kt = 0; kt < 4; ++kt)
                        afrag[s][kt] = *(const bf16x8*)(ap + kt * 32 + q * 8);
                }
            }

            // deferred col-credit flush from previous tile
            if (V == 0 && pendP) { colflush(rowsum, csumP, C0P, lane, c); pendP = false; }

            // next tile coords + prefetch-stage into the other buffer
            int trN = tr, ctN = ct + 1;
            if (ctN == 128) { trN = tr + 1; ctN = trN; }
            if (j + 1 < K_TILES) stage_tile(z, &ldsb[cur ^ 1][0], ctN << 7, wave, lane);

            const char* lb = (const char*)&ldsb[cur][0];
            float csum[8];
#pragma unroll
            for (int st = 0; st < 8; ++st) csum[st] = 0.f;

#pragma unroll
            for (int st = 0; st < 8; ++st) {
                bf16x8 bcur[4];
#pragma unroll
                for (int kt = 0; kt < 4; ++kt)
                    bcur[kt] = *(const bf16x8*)(lb + O[kt] + st * 4096);

                f32x4 acc[2] = {{0.f,0.f,0.f,0.f},{0.f,0.f,0.f,0.f}};
#pragma unroll
                for (int kt = 0; kt < 4; ++kt) {
#pragma unroll
                    for (int s = 0; s < 2; ++s)
                        acc[s] = __builtin_amdgcn_mfma_f32_16x16x32_bf16(afrag[s][kt], bcur[kt], acc[s], 0, 0, 0);
                }

                if constexpr (V == 3) {
                    // keep the MFMA results live without any epilogue (rule #17)
                    asm volatile("" :: "v"(acc[0][0]), "v"(acc[0][1]), "v"(acc[0][2]), "v"(acc[0][3]),
                                       "v"(acc[1][0]), "v"(acc[1][1]), "v"(acc[1][2]), "v"(acc[1][3]));
                } else {
                    const int gc0 = C0 + st * 16;
#pragma unroll
                    for (int s = 0; s < 2; ++s) {
                        const int R = rowW + s * 16;
                        float sp[4];
#pragma unroll
                        for (int r = 0; r < 4; ++r) {
                            float u = acc[s][r];
                            // softplus in log2 domain: max(u,0) + log2(1 + 2^-|u|)
                            float e = __builtin_amdgcn_exp2f(-fabsf(u));
                            sp[r] = fmaxf(u, 0.f) + __builtin_amdgcn_logf(1.f + e);
                        }
                        if (diag && gc0 == R) {               // zero self-similarity
#pragma unroll
                            for (int r = 0; r < 4; ++r)
                                if (c == q * 4 + r) sp[r] = 0.f;
                        }
                        if (gc0 == (R ^ Bh)) {                // positive-pair subtile
#pragma unroll
                            for (int r = 0; r < 4; ++r)
                                if (c == q * 4 + r) pospair[R + q * 4 + r] = sp[r];
                        }
#pragma unroll
                        for (int r = 0; r < 4; ++r) rs[s][r] += sp[r];
                        if (!diag) csum[st] += (sp[0] + sp[1]) + (sp[2] + sp[3]);
                    }
                }
            }

            if (V == 0 && !(ct == tr)) {    // defer the col-credit atomics past the barrier
#pragma unroll
                for (int st = 0; st < 8; ++st) csumP[st] = csum[st];
                C0P = C0;
                pendP = true;
            }

            __syncthreads();        // drains vmcnt(0): stage + atomics all a tile old
            cur ^= 1;
            tr = trN;
            ct = ctN;
        }

        if constexpr (V == 0) {
            if (pendP) colflush(rowsum, csumP, C0P, lane, c);
            if (cur_tr >= 0) flush_rs(rowsum, rowW, rs, q, c);
        }
    }
}

// ---- Kernel 3: final loss (log2-domain sums back via ln2), 16 blocks x 1024 ----
__global__ __launch_bounds__(1024) void finalize_kernel(const float* __restrict__ rowsum,
                                                        const float* __restrict__ pospair,
                                                        float* __restrict__ out) {
    __shared__ float red[16];
    const int i = blockIdx.x * 1024 + threadIdx.x;   // 16*1024 == Nn exactly
    float denom = fmaxf(LN2 * rowsum[i], EPS);
    float sp = fmaxf(LN2 * pospair[i & (Bh - 1)], EPS);   // pospair[i]==pospair[i^B]
    float acc = __logf(sp) - __logf(denom);
#pragma unroll
    for (int m = 1; m < 64; m <<= 1) acc += __shfl_xor(acc, m);
    if ((threadIdx.x & 63) == 0) red[threadIdx.x >> 6] = acc;
    __syncthreads();
    if (threadIdx.x < 16) {
        float v = red[threadIdx.x];
        v += __shfl_xor(v, 1);
        v += __shfl_xor(v, 2);
        v += __shfl_xor(v, 4);
        v += __shfl_xor(v, 8);
        if (threadIdx.x == 0) atomicAdd(out, -v / (float)Nn);
    }
}

extern "C" void kernel_launch(void* const* d_in, const int* in_sizes, int n_in,
                              void* d_out, int out_size, void* d_ws, size_t ws_size,
                              hipStream_t stream) {
    const float* za = (const float*)d_in[0];
    const float* zb = (const float*)d_in[1];

    // workspace layout: z_bf16 (4 MB) | rowsum (64 KB) | pospair (32 KB used)
    ushort* z = (ushort*)d_ws;
    float* rowsum = (float*)((char*)d_ws + (size_t)Nn * Dd * 2);
    float* pospair = rowsum + Nn;
    float* out = (float*)d_out;

    convert_kernel<<<2048, 256, 0, stream>>>((const float4*)za, (const float4*)zb, z, rowsum, out);
    main_kernel<0><<<N_BLOCKS, 256, 0, stream>>>(z, rowsum, pospair);
    finalize_kernel<<<16, 1024, 0, stream>>>(rowsum, pospair, out);
    // ---- ablation probe (writes nothing; runs after finalize) ----
    main_kernel<3><<<N_BLOCKS, 256, 0, stream>>>(z, rowsum, pospair);
}

// Round 7
// 239.205 us; speedup vs baseline: 2.1605x; 2.1605x over previous
//
#include <hip/hip_runtime.h>
#include <hip/hip_bf16.h>

// Problem constants (B=8192, D=128 from reference setup_inputs)
constexpr int Bh = 8192;
constexpr int Nn = 16384;   // 2*B
constexpr int Dd = 128;
constexpr float EPS = 1e-8f;
constexpr float LN2 = 0.69314718056f;

constexpr int K_TILES = 8;          // tiles per block
constexpr int N_TILES = 8256;       // 128x128 upper-tri tiles (incl diag): 128*129/2
constexpr int N_BLOCKS = N_TILES / K_TILES;   // 1032, exact

typedef short bf16x8 __attribute__((ext_vector_type(8)));
typedef float f32x4 __attribute__((ext_vector_type(4)));

// ---- Kernel 1: fp32 -> bf16, scaled by sqrt(2*log2e) so MFMA dot == sim/tau*log2e ----
__global__ __launch_bounds__(256) void convert_kernel(const float4* __restrict__ za,
                                                      const float4* __restrict__ zb,
                                                      ushort* __restrict__ z,
                                                      float* __restrict__ rowsum,
                                                      float* __restrict__ out) {
    const int t = blockIdx.x * 256 + threadIdx.x;        // 0 .. 524287
    constexpr int Q = (Bh * Dd) / 4;                     // 262144 float4 per input
    const float SCL = 1.69864363f;                       // sqrt(2 * 1.4426950409)
    float4 v = (t < Q) ? za[t] : zb[t - Q];
    union { ushort4 u4; __hip_bfloat16 h[4]; } cv;
    cv.h[0] = __float2bfloat16(v.x * SCL);
    cv.h[1] = __float2bfloat16(v.y * SCL);
    cv.h[2] = __float2bfloat16(v.z * SCL);
    cv.h[3] = __float2bfloat16(v.w * SCL);
    ((ushort4*)z)[t] = cv.u4;
    if (t < Nn) rowsum[t] = 0.f;
    if (t == 0) out[0] = 0.f;          // finalize accumulates via atomics
}

// tile index g -> row tile t (128-row granularity): largest t with cum(t)=t*(257-t)/2 <= g
__device__ __forceinline__ int row_tile_of(int g) {
    int t = (int)((257.0f - sqrtf(66049.0f - 8.0f * (float)g)) * 0.5f);
    t = t < 0 ? 0 : (t > 127 ? 127 : t);
    while (t * (257 - t) / 2 > g) --t;
    while ((t + 1) * (256 - t) / 2 <= g) ++t;
    return t;
}

// row-credit flush (product-trick, R7): per-lane row credit = rsm + log2(rsP),
// where rsP is the running product of (1+e) factors for this lane's column
// subset of the row (<=64 factors <= 2^64: no overflow since e<=1).
// Then 16-lane shfl-reduce, one atomic per row (log2 domain).
__device__ __forceinline__ void flush_rs(float* __restrict__ rowsum, int rowW,
                                         float (&rsm)[2][4], float (&rsP)[2][4],
                                         int q, int c) {
#pragma unroll
    for (int s = 0; s < 2; ++s)
#pragma unroll
        for (int r = 0; r < 4; ++r) {
            float v = rsm[s][r] + __builtin_amdgcn_logf(rsP[s][r]);
            v += __shfl_xor(v, 1);
            v += __shfl_xor(v, 2);
            v += __shfl_xor(v, 4);
            v += __shfl_xor(v, 8);
            if (c == 0) atomicAdd(&rowsum[rowW + s * 16 + q * 4 + r], v);
            rsm[s][r] = 0.f;
            rsP[s][r] = 1.f;
        }
}

// col-credit flush (deferred one tile): reduce over q, one atomic per col
__device__ __forceinline__ void colflush(float* __restrict__ rowsum,
                                         float (&csumP)[8], int C0P, int lane, int c) {
#pragma unroll
    for (int st = 0; st < 8; ++st) {
        float v = csumP[st];
        v += __shfl_xor(v, 16);
        v += __shfl_xor(v, 32);
        if (lane < 16) atomicAdd(&rowsum[C0P + st * 16 + c], v);
    }
}

// Stage one 128x128 bf16 B-tile (32 KB) into LDS via global_load_lds width-16.
// LDS layout XOR-swizzled via per-lane permutation of the GLOBAL source (m173);
// ds_read_b128 fragment reads are bank-conflict-free (8 words/bank).
__device__ __forceinline__ void stage_tile(const ushort* __restrict__ z, ushort* lbuf,
                                           int C0, int wave, int lane) {
#pragma unroll
    for (int i = 0; i < 8; ++i) {
        const int chunk = wave * 8 + i;              // 32 chunks of 1 KB
        const int r = (chunk << 2) + (lane >> 4);    // row 0..127 (one col of z)
        const int bl = ((lane & 15) ^ (r & 15)) << 4;  // swizzled byte-in-row
        const char* gp = (const char*)z + (((size_t)(C0 + r)) << 8) + bl;
        ushort* lp = lbuf + (chunk << 9);            // wave-uniform LDS base
        __builtin_amdgcn_global_load_lds((const __attribute__((address_space(1))) void*)gp,
                                         (__attribute__((address_space(3))) void*)lp,
                                         16, 0, 0);
    }
}

// ---- Kernel 2: R3 skeleton (staged-LDS dbuf, deferred atomics) + R7 epilogue.
// R6 ablation: skeleton = 49 us, epilogue+credits = +78 us of 127.5.
// R7 rewrites the epilogue with the product trick: since both credit paths
// SUM log2(1+e) along an axis, accumulate Π(1+e) instead and take log2 once
// per row-panel (rows) / once per 4 elements (cols). Per element: was
// 2 trans + 5-deep serial chain (exp2->add->log2->add->add), now 1.25 trans
// and chain exp2->fma. Max-terms (fmax(u,0)) accumulate separately; the
// regrouping is mathematically exact (no approximation).
__global__ __launch_bounds__(256) void main_kernel(const ushort* __restrict__ z,
                                                   float* __restrict__ rowsum,
                                                   float* __restrict__ pospair) {
    __shared__ ushort ldsb[2][16384];     // 2 x 32 KB B-tile double buffer

    const int tid = threadIdx.x;
    const int wave = tid >> 6;
    const int lane = tid & 63;
    const int q = lane >> 4;        // quad: 0..3
    const int c = lane & 15;        // 0..15
    const int g0 = blockIdx.x * K_TILES;

    int tr = row_tile_of(g0);
    int ct = tr + (g0 - tr * (257 - tr) / 2);

    // per-lane swizzled LDS fragment offsets: logical 16B-unit (q+4kt) in row c
    int O[4];
#pragma unroll
    for (int kt = 0; kt < 4; ++kt) O[kt] = (c << 8) + ((((q + 4 * kt) ^ c)) << 4);

    bf16x8 afrag[2][4];
    float rsm[2][4];    // accumulated max-terms per row
    float rsP[2][4];    // running product of (1+e) per row (this lane's cols)
#pragma unroll
    for (int s = 0; s < 2; ++s)
#pragma unroll
        for (int r = 0; r < 4; ++r) { rsm[s][r] = 0.f; rsP[s][r] = 1.f; }

    float csumP[8];
    int C0P = 0;
    bool pendP = false;
    int cur_tr = -1, rowW = 0, cur = 0;

    stage_tile(z, &ldsb[0][0], ct << 7, wave, lane);
    __syncthreads();

    for (int j = 0; j < K_TILES; ++j) {
        const int C0 = ct << 7;
        const bool diag = (ct == tr);

        if (tr != cur_tr) {                 // row-panel change: flush + reload A
            if (cur_tr >= 0) flush_rs(rowsum, rowW, rsm, rsP, q, c);
            cur_tr = tr;
            rowW = (tr << 7) + wave * 32;   // this wave's 32-row base
#pragma unroll
            for (int s = 0; s < 2; ++s) {
                const ushort* ap = z + (size_t)(rowW + s * 16 + c) * Dd;
#pragma unroll
                for (int kt = 0; kt < 4; ++kt)
                    afrag[s][kt] = *(const bf16x8*)(ap + kt * 32 + q * 8);
            }
        }

        // deferred col-credit flush from previous tile
        if (pendP) { colflush(rowsum, csumP, C0P, lane, c); pendP = false; }

        // next tile coords + prefetch-stage into the other buffer
        int trN = tr, ctN = ct + 1;
        if (ctN == 128) { trN = tr + 1; ctN = trN; }
        if (j + 1 < K_TILES) stage_tile(z, &ldsb[cur ^ 1][0], ctN << 7, wave, lane);

        const char* lb = (const char*)&ldsb[cur][0];
        float csum[8];
#pragma unroll
        for (int st = 0; st < 8; ++st) csum[st] = 0.f;

#pragma unroll
        for (int st = 0; st < 8; ++st) {
            bf16x8 bcur[4];
#pragma unroll
            for (int kt = 0; kt < 4; ++kt)
                bcur[kt] = *(const bf16x8*)(lb + O[kt] + st * 4096);

            f32x4 acc[2] = {{0.f,0.f,0.f,0.f},{0.f,0.f,0.f,0.f}};
#pragma unroll
            for (int kt = 0; kt < 4; ++kt) {
#pragma unroll
                for (int s = 0; s < 2; ++s)
                    acc[s] = __builtin_amdgcn_mfma_f32_16x16x32_bf16(afrag[s][kt], bcur[kt], acc[s], 0, 0, 0);
            }
            const int gc0 = C0 + st * 16;
#pragma unroll
            for (int s = 0; s < 2; ++s) {
                const int R = rowW + s * 16;
                float e[4], mx[4];
#pragma unroll
                for (int r = 0; r < 4; ++r) {
                    float u = acc[s][r];
                    e[r] = __builtin_amdgcn_exp2f(-fabsf(u));   // 2^-|u| in (0,1]
                    mx[r] = fmaxf(u, 0.f);
                }
                if (diag && gc0 == R) {               // zero self-similarity contribution
#pragma unroll
                    for (int r = 0; r < 4; ++r)
                        if (c == q * 4 + r) { e[r] = 0.f; mx[r] = 0.f; }
                }
                if (gc0 == (R ^ Bh)) {                // positive-pair (exact original formula)
#pragma unroll
                    for (int r = 0; r < 4; ++r)
                        if (c == q * 4 + r)
                            pospair[R + q * 4 + r] = mx[r] + __builtin_amdgcn_logf(1.f + e[r]);
                }
#pragma unroll
                for (int r = 0; r < 4; ++r) {
                    rsP[s][r] += rsP[s][r] * e[r];    // *= (1+e), single fma
                    rsm[s][r] += mx[r];
                }
                if (!diag) {   // col credit: one log2 per 4 elements
                    float t01 = 1.f + ((e[0] + e[1]) + e[0] * e[1]);   // (1+e0)(1+e1)
                    float t23 = 1.f + ((e[2] + e[3]) + e[2] * e[3]);   // (1+e2)(1+e3)
                    float ms = (mx[0] + mx[1]) + (mx[2] + mx[3]);
                    csum[st] += ms + __builtin_amdgcn_logf(t01 * t23);
                }
            }
        }

        if (!diag) {    // defer the col-credit atomics past the barrier
#pragma unroll
            for (int st = 0; st < 8; ++st) csumP[st] = csum[st];
            C0P = C0;
            pendP = true;
        }

        __syncthreads();        // drains vmcnt(0): stage + atomics all a tile old
        cur ^= 1;
        tr = trN;
        ct = ctN;
    }

    if (pendP) colflush(rowsum, csumP, C0P, lane, c);
    if (cur_tr >= 0) flush_rs(rowsum, rowW, rsm, rsP, q, c);
}

// ---- Kernel 3: final loss (log2-domain sums back via ln2), 16 blocks x 1024 ----
__global__ __launch_bounds__(1024) void finalize_kernel(const float* __restrict__ rowsum,
                                                        const float* __restrict__ pospair,
                                                        float* __restrict__ out) {
    __shared__ float red[16];
    const int i = blockIdx.x * 1024 + threadIdx.x;   // 16*1024 == Nn exactly
    float denom = fmaxf(LN2 * rowsum[i], EPS);
    float sp = fmaxf(LN2 * pospair[i & (Bh - 1)], EPS);   // pospair[i]==pospair[i^B]
    float acc = __logf(sp) - __logf(denom);
#pragma unroll
    for (int m = 1; m < 64; m <<= 1) acc += __shfl_xor(acc, m);
    if ((threadIdx.x & 63) == 0) red[threadIdx.x >> 6] = acc;
    __syncthreads();
    if (threadIdx.x < 16) {
        float v = red[threadIdx.x];
        v += __shfl_xor(v, 1);
        v += __shfl_xor(v, 2);
        v += __shfl_xor(v, 4);
        v += __shfl_xor(v, 8);
        if (threadIdx.x == 0) atomicAdd(out, -v / (float)Nn);
    }
}

extern "C" void kernel_launch(void* const* d_in, const int* in_sizes, int n_in,
                              void* d_out, int out_size, void* d_ws, size_t ws_size,
                              hipStream_t stream) {
    const float* za = (const float*)d_in[0];
    const float* zb = (const float*)d_in[1];

    // workspace layout: z_bf16 (4 MB) | rowsum (64 KB) | pospair (32 KB used)
    ushort* z = (ushort*)d_ws;
    float* rowsum = (float*)((char*)d_ws + (size_t)Nn * Dd * 2);
    float* pospair = rowsum + Nn;
    float* out = (float*)d_out;

    convert_kernel<<<2048, 256, 0, stream>>>((const float4*)za, (const float4*)zb, z, rowsum, out);
    main_kernel<<<N_BLOCKS, 256, 0, stream>>>(z, rowsum, pospair);
    finalize_kernel<<<16, 1024, 0, stream>>>(rowsum, pospair, out);
}

// Round 8
// 174.703 us; speedup vs baseline: 2.9582x; 1.3692x over previous
//
#include <hip/hip_runtime.h>
#include <hip/hip_bf16.h>

// Problem constants (B=8192, D=128 from reference setup_inputs)
constexpr int Bh = 8192;
constexpr int Nn = 16384;   // 2*B
constexpr int Dd = 128;
constexpr float EPS = 1e-8f;
constexpr float LN2 = 0.69314718056f;

constexpr int K_TILES = 8;          // tiles per block
constexpr int N_TILES = 8256;       // 128x128 upper-tri tiles (incl diag): 128*129/2
constexpr int N_BLOCKS = N_TILES / K_TILES;   // 1032, exact

typedef short bf16x8 __attribute__((ext_vector_type(8)));
typedef float f32x4 __attribute__((ext_vector_type(4)));

// ---- Kernel 1: fp32 -> bf16, scaled by sqrt(2*log2e) so MFMA dot == sim/tau*log2e ----
__global__ __launch_bounds__(256) void convert_kernel(const float4* __restrict__ za,
                                                      const float4* __restrict__ zb,
                                                      ushort* __restrict__ z,
                                                      float* __restrict__ rowsum,
                                                      float* __restrict__ out) {
    const int t = blockIdx.x * 256 + threadIdx.x;        // 0 .. 524287
    constexpr int Q = (Bh * Dd) / 4;                     // 262144 float4 per input
    const float SCL = 1.69864363f;                       // sqrt(2 * 1.4426950409)
    float4 v = (t < Q) ? za[t] : zb[t - Q];
    union { ushort4 u4; __hip_bfloat16 h[4]; } cv;
    cv.h[0] = __float2bfloat16(v.x * SCL);
    cv.h[1] = __float2bfloat16(v.y * SCL);
    cv.h[2] = __float2bfloat16(v.z * SCL);
    cv.h[3] = __float2bfloat16(v.w * SCL);
    ((ushort4*)z)[t] = cv.u4;
    if (t < Nn) rowsum[t] = 0.f;
    if (t == 0) out[0] = 0.f;          // finalize accumulates via atomics
}

// tile index g -> row tile t (128-row granularity): largest t with cum(t)=t*(257-t)/2 <= g
__device__ __forceinline__ int row_tile_of(int g) {
    int t = (int)((257.0f - sqrtf(66049.0f - 8.0f * (float)g)) * 0.5f);
    t = t < 0 ? 0 : (t > 127 ? 127 : t);
    while (t * (257 - t) / 2 > g) --t;
    while ((t + 1) * (256 - t) / 2 <= g) ++t;
    return t;
}

// row-credit flush: reduce rs over the 16 col-lanes, one atomic per row (log2 domain)
__device__ __forceinline__ void flush_rs(float* __restrict__ rowsum, int rowW,
                                         float (&rs)[2][4], int q, int c) {
#pragma unroll
    for (int s = 0; s < 2; ++s)
#pragma unroll
        for (int r = 0; r < 4; ++r) {
            float v = rs[s][r];
            v += __shfl_xor(v, 1);
            v += __shfl_xor(v, 2);
            v += __shfl_xor(v, 4);
            v += __shfl_xor(v, 8);
            if (c == 0) atomicAdd(&rowsum[rowW + s * 16 + q * 4 + r], v);
            rs[s][r] = 0.f;
        }
}

// col-credit flush (deferred one tile): reduce over q, one atomic per col
__device__ __forceinline__ void colflush(float* __restrict__ rowsum,
                                         float (&csumP)[8], int C0P, int lane, int c) {
#pragma unroll
    for (int st = 0; st < 8; ++st) {
        float v = csumP[st];
        v += __shfl_xor(v, 16);
        v += __shfl_xor(v, 32);
        if (lane < 16) atomicAdd(&rowsum[C0P + st * 16 + c], v);
    }
}

// Stage one 128x128 bf16 B-tile (32 KB) into LDS via global_load_lds width-16.
// LDS layout XOR-swizzled via per-lane permutation of the GLOBAL source (m173);
// ds_read_b128 fragment reads are bank-conflict-free (8 words/bank).
__device__ __forceinline__ void stage_tile(const ushort* __restrict__ z, ushort* lbuf,
                                           int C0, int wave, int lane) {
#pragma unroll
    for (int i = 0; i < 8; ++i) {
        const int chunk = wave * 8 + i;              // 32 chunks of 1 KB
        const int r = (chunk << 2) + (lane >> 4);    // row 0..127 (one col of z)
        const int bl = ((lane & 15) ^ (r & 15)) << 4;  // swizzled byte-in-row
        const char* gp = (const char*)z + (((size_t)(C0 + r)) << 8) + bl;
        ushort* lp = lbuf + (chunk << 9);            // wave-uniform LDS base
        __builtin_amdgcn_global_load_lds((const __attribute__((address_space(1))) void*)gp,
                                         (__attribute__((address_space(3))) void*)lp,
                                         16, 0, 0);
    }
}

// ---- Kernel 2: R3 structure + R8 acc-pipeline.
// History: R6 ablation split R3's 127.5 us into skeleton=49 + epilogue=+78.
// R4/R5/R1 falsified LDS-traffic & occupancy theories; R7 (fewer trans ops)
// REGRESSED -> the epilogue cost is serialization, not pipe throughput:
// ds_read(st)->MFMA(st)->epilogue(st) in program order stalls the wave on
// MFMA latency and acc register reuse, with only 2 waves/SIMD to cover.
// R8: two acc sets (static index under full unroll, rule #20). Phase st
// issues MFMA into acc[st&1] then runs the epilogue of acc[(st-1)&1] while
// those MFMAs execute -> the consumed acc is a full phase old, VALU work
// overlaps the wave's own matrix-pipe work. Epilogue formula = R3 verbatim.
__global__ __launch_bounds__(256) void main_kernel(const ushort* __restrict__ z,
                                                   float* __restrict__ rowsum,
                                                   float* __restrict__ pospair) {
    __shared__ ushort ldsb[2][16384];     // 2 x 32 KB B-tile double buffer

    const int tid = threadIdx.x;
    const int wave = tid >> 6;
    const int lane = tid & 63;
    const int q = lane >> 4;        // quad: 0..3
    const int c = lane & 15;        // 0..15
    const int g0 = blockIdx.x * K_TILES;

    int tr = row_tile_of(g0);
    int ct = tr + (g0 - tr * (257 - tr) / 2);

    // per-lane swizzled LDS fragment offsets: logical 16B-unit (q+4kt) in row c
    int O[4];
#pragma unroll
    for (int kt = 0; kt < 4; ++kt) O[kt] = (c << 8) + ((((q + 4 * kt) ^ c)) << 4);

    bf16x8 afrag[2][4];
    float rs[2][4];
#pragma unroll
    for (int s = 0; s < 2; ++s)
#pragma unroll
        for (int r = 0; r < 4; ++r) rs[s][r] = 0.f;

    const f32x4 Z4 = {0.f, 0.f, 0.f, 0.f};

    float csumP[8];
    int C0P = 0;
    bool pendP = false;
    int cur_tr = -1, rowW = 0, cur = 0;

    stage_tile(z, &ldsb[0][0], ct << 7, wave, lane);
    __syncthreads();

    for (int j = 0; j < K_TILES; ++j) {
        const int C0 = ct << 7;
        const bool diag = (ct == tr);

        if (tr != cur_tr) {                 // row-panel change: flush + reload A
            if (cur_tr >= 0) flush_rs(rowsum, rowW, rs, q, c);
            cur_tr = tr;
            rowW = (tr << 7) + wave * 32;   // this wave's 32-row base
#pragma unroll
            for (int s = 0; s < 2; ++s) {
                const ushort* ap = z + (size_t)(rowW + s * 16 + c) * Dd;
#pragma unroll
                for (int kt = 0; kt < 4; ++kt)
                    afrag[s][kt] = *(const bf16x8*)(ap + kt * 32 + q * 8);
            }
        }

        // deferred col-credit flush from previous tile
        if (pendP) { colflush(rowsum, csumP, C0P, lane, c); pendP = false; }

        // next tile coords + prefetch-stage into the other buffer
        int trN = tr, ctN = ct + 1;
        if (ctN == 128) { trN = tr + 1; ctN = trN; }
        if (j + 1 < K_TILES) stage_tile(z, &ldsb[cur ^ 1][0], ctN << 7, wave, lane);

        const char* lb = (const char*)&ldsb[cur][0];
        float csum[8];
#pragma unroll
        for (int st = 0; st < 8; ++st) csum[st] = 0.f;

        // ---- acc-pipelined phase loop: 9 phases over 8 st's.
        // phase st: MFMA(st) -> acc[st&1]; then epilogue(st-1) on acc[(st-1)&1].
        f32x4 acc[2][2];
#pragma unroll
        for (int st = 0; st < 9; ++st) {
            const int p = st & 1;
            if (st < 8) {
                bf16x8 bcur[4];
#pragma unroll
                for (int kt = 0; kt < 4; ++kt)
                    bcur[kt] = *(const bf16x8*)(lb + O[kt] + st * 4096);
#pragma unroll
                for (int s = 0; s < 2; ++s)
                    acc[p][s] = __builtin_amdgcn_mfma_f32_16x16x32_bf16(afrag[s][0], bcur[0], Z4, 0, 0, 0);
#pragma unroll
                for (int kt = 1; kt < 4; ++kt) {
#pragma unroll
                    for (int s = 0; s < 2; ++s)
                        acc[p][s] = __builtin_amdgcn_mfma_f32_16x16x32_bf16(afrag[s][kt], bcur[kt], acc[p][s], 0, 0, 0);
                }
            }
            if (st > 0) {
                const int stP = st - 1;         // phase being finished
                const int pp = p ^ 1;
                const int gc0 = C0 + stP * 16;
#pragma unroll
                for (int s = 0; s < 2; ++s) {
                    const int R = rowW + s * 16;
                    float sp[4];
#pragma unroll
                    for (int r = 0; r < 4; ++r) {
                        float u = acc[pp][s][r];
                        // softplus in log2 domain: max(u,0) + log2(1 + 2^-|u|)
                        float e = __builtin_amdgcn_exp2f(-fabsf(u));
                        sp[r] = fmaxf(u, 0.f) + __builtin_amdgcn_logf(1.f + e);
                    }
                    if (diag && gc0 == R) {               // zero self-similarity
#pragma unroll
                        for (int r = 0; r < 4; ++r)
                            if (c == q * 4 + r) sp[r] = 0.f;
                    }
                    if (gc0 == (R ^ Bh)) {                // positive-pair subtile
#pragma unroll
                        for (int r = 0; r < 4; ++r)
                            if (c == q * 4 + r) pospair[R + q * 4 + r] = sp[r];
                    }
#pragma unroll
                    for (int r = 0; r < 4; ++r) rs[s][r] += sp[r];
                    if (!diag) csum[stP] += (sp[0] + sp[1]) + (sp[2] + sp[3]);
                }
            }
        }

        if (!diag) {    // defer the col-credit atomics past the barrier
#pragma unroll
            for (int st = 0; st < 8; ++st) csumP[st] = csum[st];
            C0P = C0;
            pendP = true;
        }

        __syncthreads();        // drains vmcnt(0): stage + atomics all a tile old
        cur ^= 1;
        tr = trN;
        ct = ctN;
    }

    if (pendP) colflush(rowsum, csumP, C0P, lane, c);
    if (cur_tr >= 0) flush_rs(rowsum, rowW, rs, q, c);
}

// ---- Kernel 3: final loss (log2-domain sums back via ln2), 16 blocks x 1024 ----
__global__ __launch_bounds__(1024) void finalize_kernel(const float* __restrict__ rowsum,
                                                        const float* __restrict__ pospair,
                                                        float* __restrict__ out) {
    __shared__ float red[16];
    const int i = blockIdx.x * 1024 + threadIdx.x;   // 16*1024 == Nn exactly
    float denom = fmaxf(LN2 * rowsum[i], EPS);
    float sp = fmaxf(LN2 * pospair[i & (Bh - 1)], EPS);   // pospair[i]==pospair[i^B]
    float acc = __logf(sp) - __logf(denom);
#pragma unroll
    for (int m = 1; m < 64; m <<= 1) acc += __shfl_xor(acc, m);
    if ((threadIdx.x & 63) == 0) red[threadIdx.x >> 6] = acc;
    __syncthreads();
    if (threadIdx.x < 16) {
        float v = red[threadIdx.x];
        v += __shfl_xor(v, 1);
        v += __shfl_xor(v, 2);
        v += __shfl_xor(v, 4);
        v += __shfl_xor(v, 8);
        if (threadIdx.x == 0) atomicAdd(out, -v / (float)Nn);
    }
}

extern "C" void kernel_launch(void* const* d_in, const int* in_sizes, int n_in,
                              void* d_out, int out_size, void* d_ws, size_t ws_size,
                              hipStream_t stream) {
    const float* za = (const float*)d_in[0];
    const float* zb = (const float*)d_in[1];

    // workspace layout: z_bf16 (4 MB) | rowsum (64 KB) | pospair (32 KB used)
    ushort* z = (ushort*)d_ws;
    float* rowsum = (float*)((char*)d_ws + (size_t)Nn * Dd * 2);
    float* pospair = rowsum + Nn;
    float* out = (float*)d_out;

    convert_kernel<<<2048, 256, 0, stream>>>((const float4*)za, (const float4*)zb, z, rowsum, out);
    main_kernel<<<N_BLOCKS, 256, 0, stream>>>(z, rowsum, pospair);
    finalize_kernel<<<16, 1024, 0, stream>>>(rowsum, pospair, out);
}